// Round 13
// baseline (1125.540 us; speedup 1.0000x reference)
//
#include <hip/hip_runtime.h>
#include <stdint.h>

#define BTOK 16384
#define DM   512
#define DFF  2048
#define NE   8
#define NPAIR (BTOK*2)
#define MAXT 288          // max 128-row tiles total (balanced: ~264)
#define TPXMAX 36         // ceil(MAXT/8): per-XCD tile chunk upper bound

typedef short s16x8 __attribute__((ext_vector_type(8)));   // 8 bf16 in 4 VGPRs
typedef float f32x4 __attribute__((ext_vector_type(4)));

// fp32 -> bf16 RNE (inputs finite)
__device__ __forceinline__ uint16_t f2b(float f) {
  uint32_t u = __float_as_uint(f);
  u += 0x7fff + ((u >> 16) & 1);
  return (uint16_t)(u >> 16);
}

// async global->LDS, 16B per lane; lds ptr must be wave-uniform base (HW adds lane*16)
__device__ __forceinline__ void g2l16(const void* gp, void* lp) {
  __builtin_amdgcn_global_load_lds(
      (__attribute__((address_space(1))) void*)(void*)gp,
      (__attribute__((address_space(3))) void*)lp, 16, 0, 0);
}

// =====================================================================================
// k_prep: FUSED route + weight-transpose (independent pools, one dispatch).
// Blocks [0,256): gate + x->bf16. Blocks [256, 256+16384): W1/W2 transpose+convert
// with 16B vector stores. (Round 9: 383->370us confirmed.)
// =====================================================================================
__global__ __launch_bounds__(256) void k_prep(
    const float* __restrict__ x, const float* __restrict__ wg,
    int* __restrict__ counts, int* __restrict__ tk_e, float* __restrict__ tk_w,
    uint16_t* __restrict__ xb,
    const float* __restrict__ w1, const float* __restrict__ w2,
    uint16_t* __restrict__ w1t, uint16_t* __restrict__ w2t) {
  __shared__ float t[32][33];
  __shared__ int hist[NE];
  int tid = threadIdx.x;

  if (blockIdx.x >= 256) {
    // ---------------- transpose part ----------------
    int fid = blockIdx.x - 256;
    int bx = fid & 1023, z = fid >> 10;
    int R, C, c0, r0;
    const float* src;
    uint16_t* dst;
    if (z < 8) { R = DM; C = DFF; c0 = (bx & 63) * 32; r0 = (bx >> 6) * 32;
                 src = w1 + (size_t)z * R * C; dst = w1t + (size_t)z * R * C; }
    else       { R = DFF; C = DM; c0 = (bx & 15) * 32; r0 = (bx >> 4) * 32;
                 src = w2 + (size_t)(z - 8) * R * C; dst = w2t + (size_t)(z - 8) * R * C; }
    int tx = tid & 31, ty = tid >> 5;           // 32 x 8
#pragma unroll
    for (int j = 0; j < 4; j++)
      t[ty + j * 8][tx] = src[(size_t)(r0 + ty + j * 8) * C + c0 + tx];
    __syncthreads();
    int oc = tid >> 3, ch = tid & 7;            // output row oc (= src col), 16B chunk ch
    if (ch < 4) {
      uint16_t v[8];
#pragma unroll
      for (int k = 0; k < 8; k++) v[k] = f2b(t[ch * 8 + k][oc]);
      *(s16x8*)(dst + (size_t)(c0 + oc) * R + r0 + ch * 8) = *(s16x8*)v;
    }
    return;
  }

  // ---------------- route part ----------------
  int bid = blockIdx.x;
  int lane = tid & 63, wave = tid >> 6;
  if (tid < NE) hist[tid] = 0;
  __syncthreads();

  float wv[8][8];
#pragma unroll
  for (int j = 0; j < 8; j++) {
    const float4* wr = (const float4*)(wg + (size_t)(j * 64 + lane) * NE);
    float4 a = wr[0], b = wr[1];
    wv[j][0] = a.x; wv[j][1] = a.y; wv[j][2] = a.z; wv[j][3] = a.w;
    wv[j][4] = b.x; wv[j][5] = b.y; wv[j][6] = b.z; wv[j][7] = b.w;
  }

  int tok0 = bid * 64 + wave * 16;
  for (int tt = 0; tt < 16; tt++) {
    int tok = tok0 + tt;
    const float* xr = x + (size_t)tok * DM;
    float xv[8];
#pragma unroll
    for (int j = 0; j < 8; j++) xv[j] = xr[j * 64 + lane];
    float acc[NE];
#pragma unroll
    for (int e = 0; e < NE; e++) acc[e] = 0.f;
#pragma unroll
    for (int j = 0; j < 8; j++)
#pragma unroll
      for (int e = 0; e < NE; e++) acc[e] += xv[j] * wv[j][e];
#pragma unroll
    for (int e = 0; e < NE; e++) {
#pragma unroll
      for (int off = 32; off > 0; off >>= 1) acc[e] += __shfl_xor(acc[e], off, 64);
    }
    if (lane == 0) {
      float mx = acc[0];
      for (int e = 1; e < NE; e++) mx = fmaxf(mx, acc[e]);
      float p[NE], s = 0.f;
      for (int e = 0; e < NE; e++) { p[e] = __expf(acc[e] - mx); s += p[e]; }
      float inv = 1.f / s;
      int e0 = 0; float v0 = p[0];
      for (int e = 1; e < NE; e++) if (p[e] > v0) { v0 = p[e]; e0 = e; }  // strict > = top_k tiebreak
      int e1 = -1; float v1 = -1.f;
      for (int e = 0; e < NE; e++) if (e != e0 && p[e] > v1) { v1 = p[e]; e1 = e; }
      tk_e[tok * 2]     = e0; tk_w[tok * 2]     = v0 * inv;
      tk_e[tok * 2 + 1] = e1; tk_w[tok * 2 + 1] = v1 * inv;
      atomicAdd(&hist[e0], 1);
      atomicAdd(&hist[e1], 1);
    }
  }
  // convert this block's 64-token slab (L2-hot) to bf16
  const float* xs = x + (size_t)bid * 32768;
  uint16_t* xd = xb + (size_t)bid * 32768;
#pragma unroll
  for (int i = 0; i < 16; i++) {
    int o = i * 2048 + tid * 8;
    float4 a = *(const float4*)(xs + o);
    float4 b = *(const float4*)(xs + o + 4);
    uint16_t v[8] = {f2b(a.x), f2b(a.y), f2b(a.z), f2b(a.w),
                     f2b(b.x), f2b(b.y), f2b(b.z), f2b(b.w)};
    *(s16x8*)(xd + o) = *(s16x8*)v;
  }
  __syncthreads();
  if (tid < NE) atomicAdd(&counts[tid], hist[tid]);
}

// ------- build compact slot lists + (block 0) emit tile map / offsets -------
// tok_of[slot] stores the TOKEN index (r9 form for gemm1); pr_of[slot] stores the
// PAIR index (tok*2+k) for gemm2's pair-indexed y32 -> streaming combine.
__global__ __launch_bounds__(256) void k_build(const int* __restrict__ tk_e, const float* __restrict__ tk_w,
                                               const int* __restrict__ counts, int* __restrict__ cursors,
                                               int* __restrict__ tok_of, int* __restrict__ pr_of,
                                               float* __restrict__ w_of,
                                               int* __restrict__ offsets,
                                               int* __restrict__ trB, int* __restrict__ texp,
                                               int* __restrict__ ntB) {
  __shared__ int lcnt[NE], lbase[NE], soff[NE + 1];
  int tid = threadIdx.x;
  int i = blockIdx.x * 256 + tid;
  if (tid < NE) {
    lcnt[tid] = 0;
    int off = 0;
    for (int e2 = 0; e2 < tid; e2++) off += counts[e2];   // 8-wide prefix from counts
    soff[tid] = off;
  }
  __syncthreads();
  int e = tk_e[i];
  int local = atomicAdd(&lcnt[e], 1);
  __syncthreads();
  if (tid < NE) lbase[tid] = atomicAdd(&cursors[tid], lcnt[tid]);
  __syncthreads();
  int slot = soff[e] + lbase[e] + local;
  tok_of[slot] = i >> 1;            // token index (r9 form for gemm1)
  pr_of[slot] = i;                  // pair index (for gemm2 -> streaming combine)
  w_of[slot] = tk_w[i];

  // block 0: emit offsets + 128-row tile map for the GEMMs (parallel over experts)
  if (blockIdx.x == 0) {
    if (tid < NE) {
      int base = 0;
#pragma unroll
      for (int e2 = 0; e2 < NE; e2++) if (e2 < tid) base += (counts[e2] + 127) >> 7;
      int o = soff[tid];
      int n = (counts[tid] + 127) >> 7;
      for (int k = 0; k < n; k++) { trB[base + k] = o + k * 128; texp[base + k] = tid; }
      offsets[tid] = o;
    }
    if (tid == 0) {
      int nt = 0, tot = 0;
#pragma unroll
      for (int e2 = 0; e2 < NE; e2++) { nt += (counts[e2] + 127) >> 7; tot += counts[e2]; }
      *ntB = nt;
      offsets[NE] = tot;
    }
  }
}

// =====================================================================================
// Pipelined GEMM core v4: 128x256 tile, 4 waves (2x2), wave tile 64x128, acc[4][8],
// BK=32, **2-deep LDS ring (48KB) -> 3 blocks/CU** (was 3-ring/72KB/2 blocks).
// K-step restructured to 2 barriers (was 4): cluster all 12 ds_read_b128, lgkmcnt(0)
// BEFORE barrier#1 (all waves' reads of buf p complete => safe to overwrite p), then
// stage tile t+2 into p, then all 32 MFMAs, counted VM6 (outstanding <= {t+1,t+2}=12,
// VM6 => t+1 resident), barrier#2. Load slack ~1.5 K-steps (~6000cyc) >> HBM latency.
// Granule swizzle unchanged (PMC=0 conflicts). XCD-chunked block map (T1) unchanged.
// =====================================================================================

#define LDS16(off) (*(const s16x8*)((const char*)smem + (off)))
#define VM6 asm volatile("s_waitcnt vmcnt(6)" ::: "memory")
#define VM0 asm volatile("s_waitcnt vmcnt(0)" ::: "memory")
#define NOVM do{}while(0)
#define NOSTG do{}while(0)
#define MFMA16 __builtin_amdgcn_mfma_f32_16x16x32_bf16
#define BSTR 24576

#define DS0_P(bb) do{ \
  bf0 = LDS16(offB0 + (bb)*BSTR); bf1 = LDS16(offB1 + (bb)*BSTR); \
  bf2 = LDS16(offB2 + (bb)*BSTR); bf3 = LDS16(offB3 + (bb)*BSTR); \
  bf4 = LDS16(offB4 + (bb)*BSTR); bf5 = LDS16(offB5 + (bb)*BSTR); \
  bf6 = LDS16(offB6 + (bb)*BSTR); bf7 = LDS16(offB7 + (bb)*BSTR); \
  af0 = LDS16(offA0 + (bb)*BSTR); af1 = LDS16(offA1 + (bb)*BSTR); }while(0)
#define DS1_P(bb) do{ \
  af2 = LDS16(offA2 + (bb)*BSTR); af3 = LDS16(offA3 + (bb)*BSTR); }while(0)
#define SAB_P(bb) do{ \
  g2l16(gA0, (char*)smem + (bb)*BSTR + wave*1024); \
  g2l16(gA1, (char*)smem + (bb)*BSTR + 4096 + wave*1024); \
  g2l16(gB0, (char*)smem + (bb)*BSTR + 8192 + wave*1024); \
  g2l16(gB1, (char*)smem + (bb)*BSTR + 12288 + wave*1024); \
  g2l16(gB2, (char*)smem + (bb)*BSTR + 16384 + wave*1024); \
  g2l16(gB3, (char*)smem + (bb)*BSTR + 20480 + wave*1024); \
  gA0 += 32; gA1 += 32; gB0 += 32; gB1 += 32; gB2 += 32; gB3 += 32; }while(0)
#define MM16A do{ \
  __builtin_amdgcn_s_setprio(1); \
  acc[0][0] = MFMA16(af0, bf0, acc[0][0], 0, 0, 0); \
  acc[1][0] = MFMA16(af1, bf0, acc[1][0], 0, 0, 0); \
  acc[0][1] = MFMA16(af0, bf1, acc[0][1], 0, 0, 0); \
  acc[1][1] = MFMA16(af1, bf1, acc[1][1], 0, 0, 0); \
  acc[0][2] = MFMA16(af0, bf2, acc[0][2], 0, 0, 0); \
  acc[1][2] = MFMA16(af1, bf2, acc[1][2], 0, 0, 0); \
  acc[0][3] = MFMA16(af0, bf3, acc[0][3], 0, 0, 0); \
  acc[1][3] = MFMA16(af1, bf3, acc[1][3], 0, 0, 0); \
  acc[0][4] = MFMA16(af0, bf4, acc[0][4], 0, 0, 0); \
  acc[1][4] = MFMA16(af1, bf4, acc[1][4], 0, 0, 0); \
  acc[0][5] = MFMA16(af0, bf5, acc[0][5], 0, 0, 0); \
  acc[1][5] = MFMA16(af1, bf5, acc[1][5], 0, 0, 0); \
  acc[0][6] = MFMA16(af0, bf6, acc[0][6], 0, 0, 0); \
  acc[1][6] = MFMA16(af1, bf6, acc[1][6], 0, 0, 0); \
  acc[0][7] = MFMA16(af0, bf7, acc[0][7], 0, 0, 0); \
  acc[1][7] = MFMA16(af1, bf7, acc[1][7], 0, 0, 0); \
  __builtin_amdgcn_s_setprio(0); }while(0)
#define MM16B do{ \
  __builtin_amdgcn_s_setprio(1); \
  acc[2][0] = MFMA16(af2, bf0, acc[2][0], 0, 0, 0); \
  acc[3][0] = MFMA16(af3, bf0, acc[3][0], 0, 0, 0); \
  acc[2][1] = MFMA16(af2, bf1, acc[2][1], 0, 0, 0); \
  acc[3][1] = MFMA16(af3, bf1, acc[3][1], 0, 0, 0); \
  acc[2][2] = MFMA16(af2, bf2, acc[2][2], 0, 0, 0); \
  acc[3][2] = MFMA16(af3, bf2, acc[3][2], 0, 0, 0); \
  acc[2][3] = MFMA16(af2, bf3, acc[2][3], 0, 0, 0); \
  acc[3][3] = MFMA16(af3, bf3, acc[3][3], 0, 0, 0); \
  acc[2][4] = MFMA16(af2, bf4, acc[2][4], 0, 0, 0); \
  acc[3][4] = MFMA16(af3, bf4, acc[3][4], 0, 0, 0); \
  acc[2][5] = MFMA16(af2, bf5, acc[2][5], 0, 0, 0); \
  acc[3][5] = MFMA16(af3, bf5, acc[3][5], 0, 0, 0); \
  acc[2][6] = MFMA16(af2, bf6, acc[2][6], 0, 0, 0); \
  acc[3][6] = MFMA16(af3, bf6, acc[3][6], 0, 0, 0); \
  acc[2][7] = MFMA16(af2, bf7, acc[2][7], 0, 0, 0); \
  acc[3][7] = MFMA16(af3, bf7, acc[3][7], 0, 0, 0); \
  __builtin_amdgcn_s_setprio(0); }while(0)
// 2-ring K-step: reads -> lgkm0 -> barrier (buf p free) -> stage t+2 into p -> MFMAs
// -> counted vmcnt -> barrier (t+1 resident for all waves).
#define TILE2(bb, STG, VMX) do{ \
  DS0_P(bb); DS1_P(bb); \
  asm volatile("s_waitcnt lgkmcnt(0)" ::: "memory"); \
  __builtin_amdgcn_s_barrier(); \
  STG; \
  MM16A; MM16B; \
  VMX; \
  __builtin_amdgcn_s_barrier(); }while(0)

// common per-thread geometry (4 waves, 256 threads)
#define GEOM_SETUP \
  int tid = threadIdx.x, lane = tid & 63, wave = tid >> 6; \
  int wm = wave >> 1, wn = wave & 1; \
  int l15 = lane & 15, l4 = lane >> 4; \
  int offA0, offA1, offA2, offA3; \
  int offB0, offB1, offB2, offB3, offB4, offB5, offB6, offB7; \
  { int r; \
    r = wm*64 + 0*16 + l15; offA0 = r*64 + ((l4 ^ ((r>>1)&3)) << 4); \
    r = wm*64 + 1*16 + l15; offA1 = r*64 + ((l4 ^ ((r>>1)&3)) << 4); \
    r = wm*64 + 2*16 + l15; offA2 = r*64 + ((l4 ^ ((r>>1)&3)) << 4); \
    r = wm*64 + 3*16 + l15; offA3 = r*64 + ((l4 ^ ((r>>1)&3)) << 4); \
    r = wn*128 + 0*16 + l15; offB0 = 8192 + r*64 + ((l4 ^ ((r>>1)&3)) << 4); \
    r = wn*128 + 1*16 + l15; offB1 = 8192 + r*64 + ((l4 ^ ((r>>1)&3)) << 4); \
    r = wn*128 + 2*16 + l15; offB2 = 8192 + r*64 + ((l4 ^ ((r>>1)&3)) << 4); \
    r = wn*128 + 3*16 + l15; offB3 = 8192 + r*64 + ((l4 ^ ((r>>1)&3)) << 4); \
    r = wn*128 + 4*16 + l15; offB4 = 8192 + r*64 + ((l4 ^ ((r>>1)&3)) << 4); \
    r = wn*128 + 5*16 + l15; offB5 = 8192 + r*64 + ((l4 ^ ((r>>1)&3)) << 4); \
    r = wn*128 + 6*16 + l15; offB6 = 8192 + r*64 + ((l4 ^ ((r>>1)&3)) << 4); \
    r = wn*128 + 7*16 + l15; offB7 = 8192 + r*64 + ((l4 ^ ((r>>1)&3)) << 4); \
  } \
  int rp = tid >> 2, cp = (tid & 3) ^ ((rp >> 1) & 3);  /* stage: row rp(+64k), slot tid&3 */

#define ACC_INIT \
  f32x4 acc[4][8]; \
  _Pragma("unroll") for (int m = 0; m < 4; m++) \
  _Pragma("unroll") for (int n = 0; n < 8; n++) \
  _Pragma("unroll") for (int i = 0; i < 4; i++) acc[m][n][i] = 0.f; \
  s16x8 af0, af1, af2, af3, bf0, bf1, bf2, bf3, bf4, bf5, bf6, bf7;

// ---------- GEMM1: h[slot][DFF] = relu(x[tok] @ W1[e] + b1[e]); K=512, NT=16 ----------
__global__ __launch_bounds__(256, 3) void k_gemm1(
    const uint16_t* __restrict__ xb, const uint16_t* __restrict__ w1t,
    const float* __restrict__ b1,
    const int* __restrict__ tok_of, const int* __restrict__ offsets,
    const int* __restrict__ trB, const int* __restrict__ texp, const int* __restrict__ ntB,
    uint16_t* __restrict__ h) {
  __shared__ __align__(16) uint16_t smem[24576];   // 48KB: 2 bufs x (A 8KB + B 16KB)
  int id = blockIdx.x;
  int nt = *ntB, tpx = (nt + 7) >> 3;
  int x = id & 7, q = id >> 3, j = q >> 3;
  if (j >= tpx) return;
  int tile = x * tpx + j;
  if (tile >= nt) return;
  int n0 = (q & 7) * 256;
  int e = texp[tile], row0 = trB[tile], end = offsets[e + 1];
  GEOM_SETUP;

  const uint16_t *gA0, *gA1, *gB0, *gB1, *gB2, *gB3;
  { int s0 = row0 + rp;      if (s0 >= end) s0 = end - 1;
    int s1 = row0 + rp + 64; if (s1 >= end) s1 = end - 1;
    gA0 = xb + (size_t)tok_of[s0] * DM + cp * 8;
    gA1 = xb + (size_t)tok_of[s1] * DM + cp * 8; }
  { const uint16_t* wb = w1t + (size_t)e * DFF * DM;
    gB0 = wb + (size_t)(n0 + rp +   0) * DM + cp * 8;
    gB1 = wb + (size_t)(n0 + rp +  64) * DM + cp * 8;
    gB2 = wb + (size_t)(n0 + rp + 128) * DM + cp * 8;
    gB3 = wb + (size_t)(n0 + rp + 192) * DM + cp * 8; }

  ACC_INIT;

  SAB_P(0); SAB_P(1);                              // tiles 0,1 in flight (12 loads)
  VM6;                                             // tile 0 resident
  __builtin_amdgcn_s_barrier();

#pragma unroll 1
  for (int g = 0; g < 7; ++g) {                    // tiles 0..13 (stage t+2 each)
    TILE2(0, SAB_P(0), VM6);
    TILE2(1, SAB_P(1), VM6);
  }
  TILE2(0, NOSTG, VM0);                            // tile 14 (drain tile 15)
  TILE2(1, NOSTG, NOVM);                           // tile 15

  // epilogue: bias+relu -> bf16, per-wave LDS repack (row stride 272B: 16B-aligned, bank-spread)
  {
    float bv[8];
#pragma unroll
    for (int n = 0; n < 8; n++) bv[n] = b1[(size_t)e * DFF + n0 + wn * 128 + n * 16 + l15];
    char* wrg = (char*)smem + wave * 4608;
    int rr = lane >> 2, cb = lane & 3;
#pragma unroll
    for (int m = 0; m < 4; m++) {
#pragma unroll
      for (int n = 0; n < 8; n++)
#pragma unroll
        for (int i = 0; i < 4; i++) {
          float v = fmaxf(acc[m][n][i] + bv[n], 0.f);
          *(uint16_t*)(wrg + (l4 * 4 + i) * 272 + (n * 16 + l15) * 2) = f2b(v);
        }
      int gr = row0 + wm * 64 + m * 16 + rr;
      const char* src = wrg + rr * 272 + cb * 64;
      if (gr < end) {
        uint16_t* dst = h + (size_t)gr * DFF + n0 + wn * 128 + cb * 32;
        *(s16x8*)(dst +  0) = *(const s16x8*)(src +  0);
        *(s16x8*)(dst +  8) = *(const s16x8*)(src + 16);
        *(s16x8*)(dst + 16) = *(const s16x8*)(src + 32);
        *(s16x8*)(dst + 24) = *(const s16x8*)(src + 48);
      }
    }
  }
}

// ---------- GEMM2: y32[pair] = w_of[slot]*(h[slot] @ W2[e] + b2[e]); K=2048, NT=64 ----------
// Output indexed by PAIR (via pr_of) so combine is a streaming add of adjacent rows.
__global__ __launch_bounds__(256, 3) void k_gemm2(
    const uint16_t* __restrict__ h, const uint16_t* __restrict__ w2t,
    const float* __restrict__ b2, const float* __restrict__ w_of,
    const int* __restrict__ pr_of, const int* __restrict__ offsets,
    const int* __restrict__ trB, const int* __restrict__ texp, const int* __restrict__ ntB,
    float* __restrict__ y32) {
  __shared__ __align__(16) uint16_t smem[24576];   // 48KB: 2 bufs x (A 8KB + B 16KB)
  int id = blockIdx.x;
  int nt = *ntB, tpx = (nt + 7) >> 3;
  int x = id & 7, q = id >> 3, j = q >> 1;
  if (j >= tpx) return;
  int tile = x * tpx + j;
  if (tile >= nt) return;
  int n0 = (q & 1) * 256;
  int e = texp[tile], row0 = trB[tile], end = offsets[e + 1];
  GEOM_SETUP;

  const uint16_t *gA0, *gA1, *gB0, *gB1, *gB2, *gB3;
  { int s0 = row0 + rp;      if (s0 >= end) s0 = end - 1;
    int s1 = row0 + rp + 64; if (s1 >= end) s1 = end - 1;
    gA0 = h + (size_t)s0 * DFF + cp * 8;
    gA1 = h + (size_t)s1 * DFF + cp * 8; }
  { const uint16_t* wb = w2t + (size_t)e * DM * DFF;
    gB0 = wb + (size_t)(n0 + rp +   0) * DFF + cp * 8;
    gB1 = wb + (size_t)(n0 + rp +  64) * DFF + cp * 8;
    gB2 = wb + (size_t)(n0 + rp + 128) * DFF + cp * 8;
    gB3 = wb + (size_t)(n0 + rp + 192) * DFF + cp * 8; }

  ACC_INIT;

  SAB_P(0); SAB_P(1);
  VM6;
  __builtin_amdgcn_s_barrier();

#pragma unroll 1
  for (int g = 0; g < 31; ++g) {                   // tiles 0..61 (stage t+2 each)
    TILE2(0, SAB_P(0), VM6);
    TILE2(1, SAB_P(1), VM6);
  }
  TILE2(0, NOSTG, VM0);                            // tile 62 (drain tile 63)
  TILE2(1, NOSTG, NOVM);                           // tile 63

  // epilogue: weighted bias add, fp32 stores into pair-indexed y32 (16-lane 64B runs)
  {
    float bv[8];
#pragma unroll
    for (int n = 0; n < 8; n++) bv[n] = b2[(size_t)e * DM + n0 + wn * 128 + n * 16 + l15];
#pragma unroll
    for (int m = 0; m < 4; m++)
#pragma unroll
      for (int i = 0; i < 4; i++) {
        int slot = row0 + wm * 64 + m * 16 + l4 * 4 + i;
        if (slot < end) {
          float wgt = w_of[slot];
          int pr = pr_of[slot];                    // pair index = tok*2 + k
          size_t base = (size_t)pr * DM + n0 + wn * 128 + l15;
#pragma unroll
          for (int n = 0; n < 8; n++) y32[base + n * 16] = wgt * (acc[m][n][i] + bv[n]);
        }
      }
  }
}

// ---------------- combine: out[tok] = y32[2tok] + y32[2tok+1] (streaming, no indirection) ----------------
__global__ __launch_bounds__(256) void k_combine(const float* __restrict__ y32,
                                                 float* __restrict__ out) {
  int tid = threadIdx.x;
  int tok = blockIdx.x * 2 + (tid >> 7);
  int c4 = (tid & 127) * 4;
  const float4 a = *(const float4*)(y32 + (size_t)(tok * 2)     * DM + c4);
  const float4 b = *(const float4*)(y32 + (size_t)(tok * 2 + 1) * DM + c4);
  *(float4*)(out + (size_t)tok * DM + c4) = make_float4(a.x + b.x, a.y + b.y, a.z + b.z, a.w + b.w);
}

extern "C" void kernel_launch(void* const* d_in, const int* in_sizes, int n_in,
                              void* d_out, int out_size, void* d_ws, size_t ws_size,
                              hipStream_t stream) {
  const float* x  = (const float*)d_in[0];
  const float* wg = (const float*)d_in[1];
  const float* w1 = (const float*)d_in[2];
  const float* b1 = (const float*)d_in[3];
  const float* w2 = (const float*)d_in[4];
  const float* b2 = (const float*)d_in[5];
  float* out = (float*)d_out;

  char* ws = (char*)d_ws;
  const size_t MB = 1024 * 1024;
  uint16_t* xb   = (uint16_t*)ws;                  // [0,16) MB
  uint16_t* w1t  = (uint16_t*)(ws + 16 * MB);      // [16,32) MB  [E][DFF][DM]
  uint16_t* w2t  = (uint16_t*)(ws + 32 * MB);      // [32,48) MB  [E][DM][DFF]
  uint16_t* hbuf = (uint16_t*)(ws + 48 * MB);      // [48,176) MB [NPAIR][DFF]
  int* ctrl = (int*)(ws + 176 * MB);               // [176,177) MB
  int*   counts  = ctrl;                 // 0..8
  int*   cursors = ctrl + 8;             // 8..16
  int*   offsets = ctrl + 16;            // 16..25
  int*   ntB     = ctrl + 32;            // 32
  int*   trB     = ctrl + 64;            // 64..384 (320)
  int*   texp    = ctrl + 384;           // 384..704 (320)
  int*   tk_e    = ctrl + 1024;
  float* tk_w    = (float*)(ctrl + 1024 + 32768);
  int*   tok_of  = ctrl + 1024 + 2 * 32768;
  float* w_of    = (float*)(ctrl + 1024 + 3 * 32768);
  int*   pr_of   = ctrl + 1024 + 4 * 32768;
  float* y32     = (float*)(ws + 177 * MB);        // [177,241) MB fp32 [NPAIR][DM]

  hipMemsetAsync(counts, 0, 16 * sizeof(int), stream);

  k_prep<<<256 + 16384, 256, 0, stream>>>(x, wg, counts, tk_e, tk_w, xb,
                                          w1, w2, w1t, w2t);
  k_build<<<NPAIR / 256, 256, 0, stream>>>(tk_e, tk_w, counts, cursors, tok_of, pr_of, w_of,
                                           offsets, trB, texp, ntB);
  k_gemm1<<<8 * TPXMAX * 8, 256, 0, stream>>>(xb, w1t, b1, tok_of, offsets,
                                              trB, texp, ntB, hbuf);
  k_gemm2<<<8 * TPXMAX * 2, 256, 0, stream>>>(hbuf, w2t, b2, w_of, pr_of, offsets,
                                              trB, texp, ntB, y32);
  k_combine<<<BTOK / 2, 256, 0, stream>>>(y32, out);
}

// Round 14
// 363.668 us; speedup vs baseline: 3.0950x; 3.0950x over previous
//
#include <hip/hip_runtime.h>
#include <stdint.h>

#define BTOK 16384
#define DM   512
#define DFF  2048
#define NE   8
#define NPAIR (BTOK*2)
#define MAXT 288          // max 128-row tiles total (balanced: ~264)
#define TPXMAX 36         // ceil(MAXT/8): per-XCD tile chunk upper bound

typedef short s16x8 __attribute__((ext_vector_type(8)));   // 8 bf16 in 4 VGPRs
typedef float f32x4 __attribute__((ext_vector_type(4)));

// fp32 -> bf16 RNE (inputs finite)
__device__ __forceinline__ uint16_t f2b(float f) {
  uint32_t u = __float_as_uint(f);
  u += 0x7fff + ((u >> 16) & 1);
  return (uint16_t)(u >> 16);
}

// async global->LDS, 16B per lane; lds ptr must be wave-uniform base (HW adds lane*16)
__device__ __forceinline__ void g2l16(const void* gp, void* lp) {
  __builtin_amdgcn_global_load_lds(
      (__attribute__((address_space(1))) void*)(void*)gp,
      (__attribute__((address_space(3))) void*)lp, 16, 0, 0);
}

// =====================================================================================
// k_prep: FUSED route + weight-transpose (independent pools, one dispatch).
// Blocks [0,256): gate + x->bf16. Blocks [256, 256+16384): W1/W2 transpose+convert
// with 16B vector stores. (Round 9: 383->370us confirmed.)
// =====================================================================================
__global__ __launch_bounds__(256) void k_prep(
    const float* __restrict__ x, const float* __restrict__ wg,
    int* __restrict__ counts, int* __restrict__ tk_e, float* __restrict__ tk_w,
    uint16_t* __restrict__ xb,
    const float* __restrict__ w1, const float* __restrict__ w2,
    uint16_t* __restrict__ w1t, uint16_t* __restrict__ w2t) {
  __shared__ float t[32][33];
  __shared__ int hist[NE];
  int tid = threadIdx.x;

  if (blockIdx.x >= 256) {
    // ---------------- transpose part ----------------
    int fid = blockIdx.x - 256;
    int bx = fid & 1023, z = fid >> 10;
    int R, C, c0, r0;
    const float* src;
    uint16_t* dst;
    if (z < 8) { R = DM; C = DFF; c0 = (bx & 63) * 32; r0 = (bx >> 6) * 32;
                 src = w1 + (size_t)z * R * C; dst = w1t + (size_t)z * R * C; }
    else       { R = DFF; C = DM; c0 = (bx & 15) * 32; r0 = (bx >> 4) * 32;
                 src = w2 + (size_t)(z - 8) * R * C; dst = w2t + (size_t)(z - 8) * R * C; }
    int tx = tid & 31, ty = tid >> 5;           // 32 x 8
#pragma unroll
    for (int j = 0; j < 4; j++)
      t[ty + j * 8][tx] = src[(size_t)(r0 + ty + j * 8) * C + c0 + tx];
    __syncthreads();
    int oc = tid >> 3, ch = tid & 7;            // output row oc (= src col), 16B chunk ch
    if (ch < 4) {
      uint16_t v[8];
#pragma unroll
      for (int k = 0; k < 8; k++) v[k] = f2b(t[ch * 8 + k][oc]);
      *(s16x8*)(dst + (size_t)(c0 + oc) * R + r0 + ch * 8) = *(s16x8*)v;
    }
    return;
  }

  // ---------------- route part ----------------
  int bid = blockIdx.x;
  int lane = tid & 63, wave = tid >> 6;
  if (tid < NE) hist[tid] = 0;
  __syncthreads();

  float wv[8][8];
#pragma unroll
  for (int j = 0; j < 8; j++) {
    const float4* wr = (const float4*)(wg + (size_t)(j * 64 + lane) * NE);
    float4 a = wr[0], b = wr[1];
    wv[j][0] = a.x; wv[j][1] = a.y; wv[j][2] = a.z; wv[j][3] = a.w;
    wv[j][4] = b.x; wv[j][5] = b.y; wv[j][6] = b.z; wv[j][7] = b.w;
  }

  int tok0 = bid * 64 + wave * 16;
  for (int tt = 0; tt < 16; tt++) {
    int tok = tok0 + tt;
    const float* xr = x + (size_t)tok * DM;
    float xv[8];
#pragma unroll
    for (int j = 0; j < 8; j++) xv[j] = xr[j * 64 + lane];
    float acc[NE];
#pragma unroll
    for (int e = 0; e < NE; e++) acc[e] = 0.f;
#pragma unroll
    for (int j = 0; j < 8; j++)
#pragma unroll
      for (int e = 0; e < NE; e++) acc[e] += xv[j] * wv[j][e];
#pragma unroll
    for (int e = 0; e < NE; e++) {
#pragma unroll
      for (int off = 32; off > 0; off >>= 1) acc[e] += __shfl_xor(acc[e], off, 64);
    }
    if (lane == 0) {
      float mx = acc[0];
      for (int e = 1; e < NE; e++) mx = fmaxf(mx, acc[e]);
      float p[NE], s = 0.f;
      for (int e = 0; e < NE; e++) { p[e] = __expf(acc[e] - mx); s += p[e]; }
      float inv = 1.f / s;
      int e0 = 0; float v0 = p[0];
      for (int e = 1; e < NE; e++) if (p[e] > v0) { v0 = p[e]; e0 = e; }  // strict > = top_k tiebreak
      int e1 = -1; float v1 = -1.f;
      for (int e = 0; e < NE; e++) if (e != e0 && p[e] > v1) { v1 = p[e]; e1 = e; }
      tk_e[tok * 2]     = e0; tk_w[tok * 2]     = v0 * inv;
      tk_e[tok * 2 + 1] = e1; tk_w[tok * 2 + 1] = v1 * inv;
      atomicAdd(&hist[e0], 1);
      atomicAdd(&hist[e1], 1);
    }
  }
  // convert this block's 64-token slab (L2-hot) to bf16
  const float* xs = x + (size_t)bid * 32768;
  uint16_t* xd = xb + (size_t)bid * 32768;
#pragma unroll
  for (int i = 0; i < 16; i++) {
    int o = i * 2048 + tid * 8;
    float4 a = *(const float4*)(xs + o);
    float4 b = *(const float4*)(xs + o + 4);
    uint16_t v[8] = {f2b(a.x), f2b(a.y), f2b(a.z), f2b(a.w),
                     f2b(b.x), f2b(b.y), f2b(b.z), f2b(b.w)};
    *(s16x8*)(xd + o) = *(s16x8*)v;
  }
  __syncthreads();
  if (tid < NE) atomicAdd(&counts[tid], hist[tid]);
}

// ------- build compact slot lists + (block 0) emit tile map / offsets -------
// tok_of[slot] stores the TOKEN index (r9 form for gemm1); pr_of[slot] stores the
// PAIR index (tok*2+k) for gemm2's pair-indexed y32 -> streaming combine.
__global__ __launch_bounds__(256) void k_build(const int* __restrict__ tk_e, const float* __restrict__ tk_w,
                                               const int* __restrict__ counts, int* __restrict__ cursors,
                                               int* __restrict__ tok_of, int* __restrict__ pr_of,
                                               float* __restrict__ w_of,
                                               int* __restrict__ offsets,
                                               int* __restrict__ trB, int* __restrict__ texp,
                                               int* __restrict__ ntB) {
  __shared__ int lcnt[NE], lbase[NE], soff[NE + 1];
  int tid = threadIdx.x;
  int i = blockIdx.x * 256 + tid;
  if (tid < NE) {
    lcnt[tid] = 0;
    int off = 0;
    for (int e2 = 0; e2 < tid; e2++) off += counts[e2];   // 8-wide prefix from counts
    soff[tid] = off;
  }
  __syncthreads();
  int e = tk_e[i];
  int local = atomicAdd(&lcnt[e], 1);
  __syncthreads();
  if (tid < NE) lbase[tid] = atomicAdd(&cursors[tid], lcnt[tid]);
  __syncthreads();
  int slot = soff[e] + lbase[e] + local;
  tok_of[slot] = i >> 1;            // token index (r9 form for gemm1)
  pr_of[slot] = i;                  // pair index (for gemm2 -> streaming combine)
  w_of[slot] = tk_w[i];

  // block 0: emit offsets + 128-row tile map for the GEMMs (parallel over experts)
  if (blockIdx.x == 0) {
    if (tid < NE) {
      int base = 0;
#pragma unroll
      for (int e2 = 0; e2 < NE; e2++) if (e2 < tid) base += (counts[e2] + 127) >> 7;
      int o = soff[tid];
      int n = (counts[tid] + 127) >> 7;
      for (int k = 0; k < n; k++) { trB[base + k] = o + k * 128; texp[base + k] = tid; }
      offsets[tid] = o;
    }
    if (tid == 0) {
      int nt = 0, tot = 0;
#pragma unroll
      for (int e2 = 0; e2 < NE; e2++) { nt += (counts[e2] + 127) >> 7; tot += counts[e2]; }
      *ntB = nt;
      offsets[NE] = tot;
    }
  }
}

// =====================================================================================
// Pipelined GEMM core v4b: 128x256 tile, 4 waves (2x2), wave tile 64x128, acc[4][8],
// BK=32, 2-deep LDS ring (48KB), K-step with 2 barriers (was 4 in r12):
// cluster all 12 ds_read_b128, lgkmcnt(0) BEFORE barrier#1 (all waves' reads of buf p
// complete => safe to overwrite p), stage tile t+2 into p, all 32 MFMAs, counted VM6
// (outstanding <= {t+1,t+2}=12, VM6 => t+1 resident), barrier#2.
// __launch_bounds__(256, 2): ROUND-13 LESSON — (256,3) caps unified VGPR+AGPR at 170
// but the working set is ~240 (acc=128 AGPR + 48 frag + pipeline) => acc spilled to
// scratch (VGPR 84, WRITE 1.09GB, MfmaUtil 5%). Occupancy is register-capped at
// 2 blocks/CU for this geometry regardless of LDS.
// Granule swizzle unchanged (PMC=0 conflicts). XCD-chunked block map (T1) unchanged.
// =====================================================================================

#define LDS16(off) (*(const s16x8*)((const char*)smem + (off)))
#define VM6 asm volatile("s_waitcnt vmcnt(6)" ::: "memory")
#define VM0 asm volatile("s_waitcnt vmcnt(0)" ::: "memory")
#define NOVM do{}while(0)
#define NOSTG do{}while(0)
#define MFMA16 __builtin_amdgcn_mfma_f32_16x16x32_bf16
#define BSTR 24576

#define DS0_P(bb) do{ \
  bf0 = LDS16(offB0 + (bb)*BSTR); bf1 = LDS16(offB1 + (bb)*BSTR); \
  bf2 = LDS16(offB2 + (bb)*BSTR); bf3 = LDS16(offB3 + (bb)*BSTR); \
  bf4 = LDS16(offB4 + (bb)*BSTR); bf5 = LDS16(offB5 + (bb)*BSTR); \
  bf6 = LDS16(offB6 + (bb)*BSTR); bf7 = LDS16(offB7 + (bb)*BSTR); \
  af0 = LDS16(offA0 + (bb)*BSTR); af1 = LDS16(offA1 + (bb)*BSTR); }while(0)
#define DS1_P(bb) do{ \
  af2 = LDS16(offA2 + (bb)*BSTR); af3 = LDS16(offA3 + (bb)*BSTR); }while(0)
#define SAB_P(bb) do{ \
  g2l16(gA0, (char*)smem + (bb)*BSTR + wave*1024); \
  g2l16(gA1, (char*)smem + (bb)*BSTR + 4096 + wave*1024); \
  g2l16(gB0, (char*)smem + (bb)*BSTR + 8192 + wave*1024); \
  g2l16(gB1, (char*)smem + (bb)*BSTR + 12288 + wave*1024); \
  g2l16(gB2, (char*)smem + (bb)*BSTR + 16384 + wave*1024); \
  g2l16(gB3, (char*)smem + (bb)*BSTR + 20480 + wave*1024); \
  gA0 += 32; gA1 += 32; gB0 += 32; gB1 += 32; gB2 += 32; gB3 += 32; }while(0)
#define MM16A do{ \
  __builtin_amdgcn_s_setprio(1); \
  acc[0][0] = MFMA16(af0, bf0, acc[0][0], 0, 0, 0); \
  acc[1][0] = MFMA16(af1, bf0, acc[1][0], 0, 0, 0); \
  acc[0][1] = MFMA16(af0, bf1, acc[0][1], 0, 0, 0); \
  acc[1][1] = MFMA16(af1, bf1, acc[1][1], 0, 0, 0); \
  acc[0][2] = MFMA16(af0, bf2, acc[0][2], 0, 0, 0); \
  acc[1][2] = MFMA16(af1, bf2, acc[1][2], 0, 0, 0); \
  acc[0][3] = MFMA16(af0, bf3, acc[0][3], 0, 0, 0); \
  acc[1][3] = MFMA16(af1, bf3, acc[1][3], 0, 0, 0); \
  acc[0][4] = MFMA16(af0, bf4, acc[0][4], 0, 0, 0); \
  acc[1][4] = MFMA16(af1, bf4, acc[1][4], 0, 0, 0); \
  acc[0][5] = MFMA16(af0, bf5, acc[0][5], 0, 0, 0); \
  acc[1][5] = MFMA16(af1, bf5, acc[1][5], 0, 0, 0); \
  acc[0][6] = MFMA16(af0, bf6, acc[0][6], 0, 0, 0); \
  acc[1][6] = MFMA16(af1, bf6, acc[1][6], 0, 0, 0); \
  acc[0][7] = MFMA16(af0, bf7, acc[0][7], 0, 0, 0); \
  acc[1][7] = MFMA16(af1, bf7, acc[1][7], 0, 0, 0); \
  __builtin_amdgcn_s_setprio(0); }while(0)
#define MM16B do{ \
  __builtin_amdgcn_s_setprio(1); \
  acc[2][0] = MFMA16(af2, bf0, acc[2][0], 0, 0, 0); \
  acc[3][0] = MFMA16(af3, bf0, acc[3][0], 0, 0, 0); \
  acc[2][1] = MFMA16(af2, bf1, acc[2][1], 0, 0, 0); \
  acc[3][1] = MFMA16(af3, bf1, acc[3][1], 0, 0, 0); \
  acc[2][2] = MFMA16(af2, bf2, acc[2][2], 0, 0, 0); \
  acc[3][2] = MFMA16(af3, bf2, acc[3][2], 0, 0, 0); \
  acc[2][3] = MFMA16(af2, bf3, acc[2][3], 0, 0, 0); \
  acc[3][3] = MFMA16(af3, bf3, acc[3][3], 0, 0, 0); \
  acc[2][4] = MFMA16(af2, bf4, acc[2][4], 0, 0, 0); \
  acc[3][4] = MFMA16(af3, bf4, acc[3][4], 0, 0, 0); \
  acc[2][5] = MFMA16(af2, bf5, acc[2][5], 0, 0, 0); \
  acc[3][5] = MFMA16(af3, bf5, acc[3][5], 0, 0, 0); \
  acc[2][6] = MFMA16(af2, bf6, acc[2][6], 0, 0, 0); \
  acc[3][6] = MFMA16(af3, bf6, acc[3][6], 0, 0, 0); \
  acc[2][7] = MFMA16(af2, bf7, acc[2][7], 0, 0, 0); \
  acc[3][7] = MFMA16(af3, bf7, acc[3][7], 0, 0, 0); \
  __builtin_amdgcn_s_setprio(0); }while(0)
// 2-ring K-step: reads -> lgkm0 -> barrier (buf p free) -> stage t+2 into p -> MFMAs
// -> counted vmcnt -> barrier (t+1 resident for all waves).
#define TILE2(bb, STG, VMX) do{ \
  DS0_P(bb); DS1_P(bb); \
  asm volatile("s_waitcnt lgkmcnt(0)" ::: "memory"); \
  __builtin_amdgcn_s_barrier(); \
  STG; \
  MM16A; MM16B; \
  VMX; \
  __builtin_amdgcn_s_barrier(); }while(0)

// common per-thread geometry (4 waves, 256 threads)
#define GEOM_SETUP \
  int tid = threadIdx.x, lane = tid & 63, wave = tid >> 6; \
  int wm = wave >> 1, wn = wave & 1; \
  int l15 = lane & 15, l4 = lane >> 4; \
  int offA0, offA1, offA2, offA3; \
  int offB0, offB1, offB2, offB3, offB4, offB5, offB6, offB7; \
  { int r; \
    r = wm*64 + 0*16 + l15; offA0 = r*64 + ((l4 ^ ((r>>1)&3)) << 4); \
    r = wm*64 + 1*16 + l15; offA1 = r*64 + ((l4 ^ ((r>>1)&3)) << 4); \
    r = wm*64 + 2*16 + l15; offA2 = r*64 + ((l4 ^ ((r>>1)&3)) << 4); \
    r = wm*64 + 3*16 + l15; offA3 = r*64 + ((l4 ^ ((r>>1)&3)) << 4); \
    r = wn*128 + 0*16 + l15; offB0 = 8192 + r*64 + ((l4 ^ ((r>>1)&3)) << 4); \
    r = wn*128 + 1*16 + l15; offB1 = 8192 + r*64 + ((l4 ^ ((r>>1)&3)) << 4); \
    r = wn*128 + 2*16 + l15; offB2 = 8192 + r*64 + ((l4 ^ ((r>>1)&3)) << 4); \
    r = wn*128 + 3*16 + l15; offB3 = 8192 + r*64 + ((l4 ^ ((r>>1)&3)) << 4); \
    r = wn*128 + 4*16 + l15; offB4 = 8192 + r*64 + ((l4 ^ ((r>>1)&3)) << 4); \
    r = wn*128 + 5*16 + l15; offB5 = 8192 + r*64 + ((l4 ^ ((r>>1)&3)) << 4); \
    r = wn*128 + 6*16 + l15; offB6 = 8192 + r*64 + ((l4 ^ ((r>>1)&3)) << 4); \
    r = wn*128 + 7*16 + l15; offB7 = 8192 + r*64 + ((l4 ^ ((r>>1)&3)) << 4); \
  } \
  int rp = tid >> 2, cp = (tid & 3) ^ ((rp >> 1) & 3);  /* stage: row rp(+64k), slot tid&3 */

#define ACC_INIT \
  f32x4 acc[4][8]; \
  _Pragma("unroll") for (int m = 0; m < 4; m++) \
  _Pragma("unroll") for (int n = 0; n < 8; n++) \
  _Pragma("unroll") for (int i = 0; i < 4; i++) acc[m][n][i] = 0.f; \
  s16x8 af0, af1, af2, af3, bf0, bf1, bf2, bf3, bf4, bf5, bf6, bf7;

// ---------- GEMM1: h[slot][DFF] = relu(x[tok] @ W1[e] + b1[e]); K=512, NT=16 ----------
__global__ __launch_bounds__(256, 2) void k_gemm1(
    const uint16_t* __restrict__ xb, const uint16_t* __restrict__ w1t,
    const float* __restrict__ b1,
    const int* __restrict__ tok_of, const int* __restrict__ offsets,
    const int* __restrict__ trB, const int* __restrict__ texp, const int* __restrict__ ntB,
    uint16_t* __restrict__ h) {
  __shared__ __align__(16) uint16_t smem[24576];   // 48KB: 2 bufs x (A 8KB + B 16KB)
  int id = blockIdx.x;
  int nt = *ntB, tpx = (nt + 7) >> 3;
  int x = id & 7, q = id >> 3, j = q >> 3;
  if (j >= tpx) return;
  int tile = x * tpx + j;
  if (tile >= nt) return;
  int n0 = (q & 7) * 256;
  int e = texp[tile], row0 = trB[tile], end = offsets[e + 1];
  GEOM_SETUP;

  const uint16_t *gA0, *gA1, *gB0, *gB1, *gB2, *gB3;
  { int s0 = row0 + rp;      if (s0 >= end) s0 = end - 1;
    int s1 = row0 + rp + 64; if (s1 >= end) s1 = end - 1;
    gA0 = xb + (size_t)tok_of[s0] * DM + cp * 8;
    gA1 = xb + (size_t)tok_of[s1] * DM + cp * 8; }
  { const uint16_t* wb = w1t + (size_t)e * DFF * DM;
    gB0 = wb + (size_t)(n0 + rp +   0) * DM + cp * 8;
    gB1 = wb + (size_t)(n0 + rp +  64) * DM + cp * 8;
    gB2 = wb + (size_t)(n0 + rp + 128) * DM + cp * 8;
    gB3 = wb + (size_t)(n0 + rp + 192) * DM + cp * 8; }

  ACC_INIT;

  SAB_P(0); SAB_P(1);                              // tiles 0,1 in flight (12 loads)
  VM6;                                             // tile 0 resident
  __builtin_amdgcn_s_barrier();

#pragma unroll 1
  for (int g = 0; g < 7; ++g) {                    // tiles 0..13 (stage t+2 each)
    TILE2(0, SAB_P(0), VM6);
    TILE2(1, SAB_P(1), VM6);
  }
  TILE2(0, NOSTG, VM0);                            // tile 14 (drain tile 15)
  TILE2(1, NOSTG, NOVM);                           // tile 15

  // epilogue: bias+relu -> bf16, per-wave LDS repack (row stride 272B: 16B-aligned, bank-spread)
  {
    float bv[8];
#pragma unroll
    for (int n = 0; n < 8; n++) bv[n] = b1[(size_t)e * DFF + n0 + wn * 128 + n * 16 + l15];
    char* wrg = (char*)smem + wave * 4608;
    int rr = lane >> 2, cb = lane & 3;
#pragma unroll
    for (int m = 0; m < 4; m++) {
#pragma unroll
      for (int n = 0; n < 8; n++)
#pragma unroll
        for (int i = 0; i < 4; i++) {
          float v = fmaxf(acc[m][n][i] + bv[n], 0.f);
          *(uint16_t*)(wrg + (l4 * 4 + i) * 272 + (n * 16 + l15) * 2) = f2b(v);
        }
      int gr = row0 + wm * 64 + m * 16 + rr;
      const char* src = wrg + rr * 272 + cb * 64;
      if (gr < end) {
        uint16_t* dst = h + (size_t)gr * DFF + n0 + wn * 128 + cb * 32;
        *(s16x8*)(dst +  0) = *(const s16x8*)(src +  0);
        *(s16x8*)(dst +  8) = *(const s16x8*)(src + 16);
        *(s16x8*)(dst + 16) = *(const s16x8*)(src + 32);
        *(s16x8*)(dst + 24) = *(const s16x8*)(src + 48);
      }
    }
  }
}

// ---------- GEMM2: y32[pair] = w_of[slot]*(h[slot] @ W2[e] + b2[e]); K=2048, NT=64 ----------
// Output indexed by PAIR (via pr_of) so combine is a streaming add of adjacent rows.
__global__ __launch_bounds__(256, 2) void k_gemm2(
    const uint16_t* __restrict__ h, const uint16_t* __restrict__ w2t,
    const float* __restrict__ b2, const float* __restrict__ w_of,
    const int* __restrict__ pr_of, const int* __restrict__ offsets,
    const int* __restrict__ trB, const int* __restrict__ texp, const int* __restrict__ ntB,
    float* __restrict__ y32) {
  __shared__ __align__(16) uint16_t smem[24576];   // 48KB: 2 bufs x (A 8KB + B 16KB)
  int id = blockIdx.x;
  int nt = *ntB, tpx = (nt + 7) >> 3;
  int x = id & 7, q = id >> 3, j = q >> 1;
  if (j >= tpx) return;
  int tile = x * tpx + j;
  if (tile >= nt) return;
  int n0 = (q & 1) * 256;
  int e = texp[tile], row0 = trB[tile], end = offsets[e + 1];
  GEOM_SETUP;

  const uint16_t *gA0, *gA1, *gB0, *gB1, *gB2, *gB3;
  { int s0 = row0 + rp;      if (s0 >= end) s0 = end - 1;
    int s1 = row0 + rp + 64; if (s1 >= end) s1 = end - 1;
    gA0 = h + (size_t)s0 * DFF + cp * 8;
    gA1 = h + (size_t)s1 * DFF + cp * 8; }
  { const uint16_t* wb = w2t + (size_t)e * DM * DFF;
    gB0 = wb + (size_t)(n0 + rp +   0) * DFF + cp * 8;
    gB1 = wb + (size_t)(n0 + rp +  64) * DFF + cp * 8;
    gB2 = wb + (size_t)(n0 + rp + 128) * DFF + cp * 8;
    gB3 = wb + (size_t)(n0 + rp + 192) * DFF + cp * 8; }

  ACC_INIT;

  SAB_P(0); SAB_P(1);
  VM6;
  __builtin_amdgcn_s_barrier();

#pragma unroll 1
  for (int g = 0; g < 31; ++g) {                   // tiles 0..61 (stage t+2 each)
    TILE2(0, SAB_P(0), VM6);
    TILE2(1, SAB_P(1), VM6);
  }
  TILE2(0, NOSTG, VM0);                            // tile 62 (drain tile 63)
  TILE2(1, NOSTG, NOVM);                           // tile 63

  // epilogue: weighted bias add, fp32 stores into pair-indexed y32 (16-lane 64B runs)
  {
    float bv[8];
#pragma unroll
    for (int n = 0; n < 8; n++) bv[n] = b2[(size_t)e * DM + n0 + wn * 128 + n * 16 + l15];
#pragma unroll
    for (int m = 0; m < 4; m++)
#pragma unroll
      for (int i = 0; i < 4; i++) {
        int slot = row0 + wm * 64 + m * 16 + l4 * 4 + i;
        if (slot < end) {
          float wgt = w_of[slot];
          int pr = pr_of[slot];                    // pair index = tok*2 + k
          size_t base = (size_t)pr * DM + n0 + wn * 128 + l15;
#pragma unroll
          for (int n = 0; n < 8; n++) y32[base + n * 16] = wgt * (acc[m][n][i] + bv[n]);
        }
      }
  }
}

// ---------------- combine: out[tok] = y32[2tok] + y32[2tok+1] (streaming, no indirection) ----------------
__global__ __launch_bounds__(256) void k_combine(const float* __restrict__ y32,
                                                 float* __restrict__ out) {
  int tid = threadIdx.x;
  int tok = blockIdx.x * 2 + (tid >> 7);
  int c4 = (tid & 127) * 4;
  const float4 a = *(const float4*)(y32 + (size_t)(tok * 2)     * DM + c4);
  const float4 b = *(const float4*)(y32 + (size_t)(tok * 2 + 1) * DM + c4);
  *(float4*)(out + (size_t)tok * DM + c4) = make_float4(a.x + b.x, a.y + b.y, a.z + b.z, a.w + b.w);
}

extern "C" void kernel_launch(void* const* d_in, const int* in_sizes, int n_in,
                              void* d_out, int out_size, void* d_ws, size_t ws_size,
                              hipStream_t stream) {
  const float* x  = (const float*)d_in[0];
  const float* wg = (const float*)d_in[1];
  const float* w1 = (const float*)d_in[2];
  const float* b1 = (const float*)d_in[3];
  const float* w2 = (const float*)d_in[4];
  const float* b2 = (const float*)d_in[5];
  float* out = (float*)d_out;

  char* ws = (char*)d_ws;
  const size_t MB = 1024 * 1024;
  uint16_t* xb   = (uint16_t*)ws;                  // [0,16) MB
  uint16_t* w1t  = (uint16_t*)(ws + 16 * MB);      // [16,32) MB  [E][DFF][DM]
  uint16_t* w2t  = (uint16_t*)(ws + 32 * MB);      // [32,48) MB  [E][DM][DFF]
  uint16_t* hbuf = (uint16_t*)(ws + 48 * MB);      // [48,176) MB [NPAIR][DFF]
  int* ctrl = (int*)(ws + 176 * MB);               // [176,177) MB
  int*   counts  = ctrl;                 // 0..8
  int*   cursors = ctrl + 8;             // 8..16
  int*   offsets = ctrl + 16;            // 16..25
  int*   ntB     = ctrl + 32;            // 32
  int*   trB     = ctrl + 64;            // 64..384 (320)
  int*   texp    = ctrl + 384;           // 384..704 (320)
  int*   tk_e    = ctrl + 1024;
  float* tk_w    = (float*)(ctrl + 1024 + 32768);
  int*   tok_of  = ctrl + 1024 + 2 * 32768;
  float* w_of    = (float*)(ctrl + 1024 + 3 * 32768);
  int*   pr_of   = ctrl + 1024 + 4 * 32768;
  float* y32     = (float*)(ws + 177 * MB);        // [177,241) MB fp32 [NPAIR][DM]

  hipMemsetAsync(counts, 0, 16 * sizeof(int), stream);

  k_prep<<<256 + 16384, 256, 0, stream>>>(x, wg, counts, tk_e, tk_w, xb,
                                          w1, w2, w1t, w2t);
  k_build<<<NPAIR / 256, 256, 0, stream>>>(tk_e, tk_w, counts, cursors, tok_of, pr_of, w_of,
                                           offsets, trB, texp, ntB);
  k_gemm1<<<8 * TPXMAX * 8, 256, 0, stream>>>(xb, w1t, b1, tok_of, offsets,
                                              trB, texp, ntB, hbuf);
  k_gemm2<<<8 * TPXMAX * 2, 256, 0, stream>>>(hbuf, w2t, b2, w_of, pr_of, offsets,
                                              trB, texp, ntB, y32);
  k_combine<<<BTOK / 2, 256, 0, stream>>>(y32, out);
}

// Round 15
// 350.725 us; speedup vs baseline: 3.2092x; 1.0369x over previous
//
#include <hip/hip_runtime.h>
#include <stdint.h>

#define BTOK 16384
#define DM   512
#define DFF  2048
#define NE   8
#define NPAIR (BTOK*2)
#define MAXT 288          // max 128-row tiles total (balanced: ~264)
#define TPXMAX 36         // ceil(MAXT/8): per-XCD tile chunk upper bound

typedef short s16x8 __attribute__((ext_vector_type(8)));   // 8 bf16 in 4 VGPRs
typedef float f32x4 __attribute__((ext_vector_type(4)));

// fp32 -> bf16 RNE (inputs finite)
__device__ __forceinline__ uint16_t f2b(float f) {
  uint32_t u = __float_as_uint(f);
  u += 0x7fff + ((u >> 16) & 1);
  return (uint16_t)(u >> 16);
}

// async global->LDS, 16B per lane; lds ptr must be wave-uniform base (HW adds lane*16)
__device__ __forceinline__ void g2l16(const void* gp, void* lp) {
  __builtin_amdgcn_global_load_lds(
      (__attribute__((address_space(1))) void*)(void*)gp,
      (__attribute__((address_space(3))) void*)lp, 16, 0, 0);
}

// =====================================================================================
// k_prep: FUSED route + weight-transpose (unchanged, round-9 confirmed).
// =====================================================================================
__global__ __launch_bounds__(256) void k_prep(
    const float* __restrict__ x, const float* __restrict__ wg,
    int* __restrict__ counts, int* __restrict__ tk_e, float* __restrict__ tk_w,
    uint16_t* __restrict__ xb,
    const float* __restrict__ w1, const float* __restrict__ w2,
    uint16_t* __restrict__ w1t, uint16_t* __restrict__ w2t) {
  __shared__ float t[32][33];
  __shared__ int hist[NE];
  int tid = threadIdx.x;

  if (blockIdx.x >= 256) {
    int fid = blockIdx.x - 256;
    int bx = fid & 1023, z = fid >> 10;
    int R, C, c0, r0;
    const float* src;
    uint16_t* dst;
    if (z < 8) { R = DM; C = DFF; c0 = (bx & 63) * 32; r0 = (bx >> 6) * 32;
                 src = w1 + (size_t)z * R * C; dst = w1t + (size_t)z * R * C; }
    else       { R = DFF; C = DM; c0 = (bx & 15) * 32; r0 = (bx >> 4) * 32;
                 src = w2 + (size_t)(z - 8) * R * C; dst = w2t + (size_t)(z - 8) * R * C; }
    int tx = tid & 31, ty = tid >> 5;           // 32 x 8
#pragma unroll
    for (int j = 0; j < 4; j++)
      t[ty + j * 8][tx] = src[(size_t)(r0 + ty + j * 8) * C + c0 + tx];
    __syncthreads();
    int oc = tid >> 3, ch = tid & 7;
    if (ch < 4) {
      uint16_t v[8];
#pragma unroll
      for (int k = 0; k < 8; k++) v[k] = f2b(t[ch * 8 + k][oc]);
      *(s16x8*)(dst + (size_t)(c0 + oc) * R + r0 + ch * 8) = *(s16x8*)v;
    }
    return;
  }

  int bid = blockIdx.x;
  int lane = tid & 63, wave = tid >> 6;
  if (tid < NE) hist[tid] = 0;
  __syncthreads();

  float wv[8][8];
#pragma unroll
  for (int j = 0; j < 8; j++) {
    const float4* wr = (const float4*)(wg + (size_t)(j * 64 + lane) * NE);
    float4 a = wr[0], b = wr[1];
    wv[j][0] = a.x; wv[j][1] = a.y; wv[j][2] = a.z; wv[j][3] = a.w;
    wv[j][4] = b.x; wv[j][5] = b.y; wv[j][6] = b.z; wv[j][7] = b.w;
  }

  int tok0 = bid * 64 + wave * 16;
  for (int tt = 0; tt < 16; tt++) {
    int tok = tok0 + tt;
    const float* xr = x + (size_t)tok * DM;
    float xv[8];
#pragma unroll
    for (int j = 0; j < 8; j++) xv[j] = xr[j * 64 + lane];
    float acc[NE];
#pragma unroll
    for (int e = 0; e < NE; e++) acc[e] = 0.f;
#pragma unroll
    for (int j = 0; j < 8; j++)
#pragma unroll
      for (int e = 0; e < NE; e++) acc[e] += xv[j] * wv[j][e];
#pragma unroll
    for (int e = 0; e < NE; e++) {
#pragma unroll
      for (int off = 32; off > 0; off >>= 1) acc[e] += __shfl_xor(acc[e], off, 64);
    }
    if (lane == 0) {
      float mx = acc[0];
      for (int e = 1; e < NE; e++) mx = fmaxf(mx, acc[e]);
      float p[NE], s = 0.f;
      for (int e = 0; e < NE; e++) { p[e] = __expf(acc[e] - mx); s += p[e]; }
      float inv = 1.f / s;
      int e0 = 0; float v0 = p[0];
      for (int e = 1; e < NE; e++) if (p[e] > v0) { v0 = p[e]; e0 = e; }  // strict > = top_k tiebreak
      int e1 = -1; float v1 = -1.f;
      for (int e = 0; e < NE; e++) if (e != e0 && p[e] > v1) { v1 = p[e]; e1 = e; }
      tk_e[tok * 2]     = e0; tk_w[tok * 2]     = v0 * inv;
      tk_e[tok * 2 + 1] = e1; tk_w[tok * 2 + 1] = v1 * inv;
      atomicAdd(&hist[e0], 1);
      atomicAdd(&hist[e1], 1);
    }
  }
  const float* xs = x + (size_t)bid * 32768;
  uint16_t* xd = xb + (size_t)bid * 32768;
#pragma unroll
  for (int i = 0; i < 16; i++) {
    int o = i * 2048 + tid * 8;
    float4 a = *(const float4*)(xs + o);
    float4 b = *(const float4*)(xs + o + 4);
    uint16_t v[8] = {f2b(a.x), f2b(a.y), f2b(a.z), f2b(a.w),
                     f2b(b.x), f2b(b.y), f2b(b.z), f2b(b.w)};
    *(s16x8*)(xd + o) = *(s16x8*)v;
  }
  __syncthreads();
  if (tid < NE) atomicAdd(&counts[tid], hist[tid]);
}

// ------- build compact slot lists + (block 0) emit tile map / offsets (unchanged) -------
__global__ __launch_bounds__(256) void k_build(const int* __restrict__ tk_e, const float* __restrict__ tk_w,
                                               const int* __restrict__ counts, int* __restrict__ cursors,
                                               int* __restrict__ tok_of, int* __restrict__ pr_of,
                                               float* __restrict__ w_of,
                                               int* __restrict__ offsets,
                                               int* __restrict__ trB, int* __restrict__ texp,
                                               int* __restrict__ ntB) {
  __shared__ int lcnt[NE], lbase[NE], soff[NE + 1];
  int tid = threadIdx.x;
  int i = blockIdx.x * 256 + tid;
  if (tid < NE) {
    lcnt[tid] = 0;
    int off = 0;
    for (int e2 = 0; e2 < tid; e2++) off += counts[e2];
    soff[tid] = off;
  }
  __syncthreads();
  int e = tk_e[i];
  int local = atomicAdd(&lcnt[e], 1);
  __syncthreads();
  if (tid < NE) lbase[tid] = atomicAdd(&cursors[tid], lcnt[tid]);
  __syncthreads();
  int slot = soff[e] + lbase[e] + local;
  tok_of[slot] = i >> 1;            // token index
  pr_of[slot] = i;                  // pair index
  w_of[slot] = tk_w[i];

  if (blockIdx.x == 0) {
    if (tid < NE) {
      int base = 0;
#pragma unroll
      for (int e2 = 0; e2 < NE; e2++) if (e2 < tid) base += (counts[e2] + 127) >> 7;
      int o = soff[tid];
      int n = (counts[tid] + 127) >> 7;
      for (int k = 0; k < n; k++) { trB[base + k] = o + k * 128; texp[base + k] = tid; }
      offsets[tid] = o;
    }
    if (tid == 0) {
      int nt = 0, tot = 0;
#pragma unroll
      for (int e2 = 0; e2 < NE; e2++) { nt += (counts[e2] + 127) >> 7; tot += counts[e2]; }
      *ntB = nt;
      offsets[NE] = tot;
    }
  }
}

// =====================================================================================
// GEMM core v5: 128x128 tile, 4 waves (2x2), wave tile 64x64, acc[4][4] (64 AGPR),
// BK=32, 3-deep LDS ring (48KB), 2-barrier K-step, stage t+3, counted VM8/VM4/VM0
// (4 loads/thread/tile; outstanding <= {t+1,t+2,t+3}=12 => VM8 -> t+1 resident).
// __launch_bounds__(256,3): reg footprint ~92 VGPR + 64 AGPR = 156 <= 170 cap
// => 3 blocks/CU = 768 slots. Rationale (r14 makespan model): uniform blocks +
// nwg%slots != 0 => gemm2 tail doubled its makespan (528/512, ~52us idle); finer
// blocks + more slots cut both tails. Round-13 lesson honored: this geometry FITS
// the (256,3) cap (the 240-reg 64x128 tile did not).
// Granule swizzle + XCD-chunked map unchanged (PMC=0 conflicts, FETCH-confirmed).
// =====================================================================================

#define LDS16(off) (*(const s16x8*)((const char*)smem + (off)))
#define VM8 asm volatile("s_waitcnt vmcnt(8)" ::: "memory")
#define VM4 asm volatile("s_waitcnt vmcnt(4)" ::: "memory")
#define VM0 asm volatile("s_waitcnt vmcnt(0)" ::: "memory")
#define NOVM do{}while(0)
#define NOSTG do{}while(0)
#define MFMA16 __builtin_amdgcn_mfma_f32_16x16x32_bf16
#define BSTR 16384

#define DS_ALL(bb) do{ \
  bf0 = LDS16(offB0 + (bb)*BSTR); bf1 = LDS16(offB1 + (bb)*BSTR); \
  bf2 = LDS16(offB2 + (bb)*BSTR); bf3 = LDS16(offB3 + (bb)*BSTR); \
  af0 = LDS16(offA0 + (bb)*BSTR); af1 = LDS16(offA1 + (bb)*BSTR); \
  af2 = LDS16(offA2 + (bb)*BSTR); af3 = LDS16(offA3 + (bb)*BSTR); }while(0)
#define SAB_P(bb) do{ \
  g2l16(gA0, (char*)smem + (bb)*BSTR + wave*1024); \
  g2l16(gA1, (char*)smem + (bb)*BSTR + 4096 + wave*1024); \
  g2l16(gB0, (char*)smem + (bb)*BSTR + 8192 + wave*1024); \
  g2l16(gB1, (char*)smem + (bb)*BSTR + 12288 + wave*1024); \
  gA0 += 32; gA1 += 32; gB0 += 32; gB1 += 32; }while(0)
#define MM16 do{ \
  __builtin_amdgcn_s_setprio(1); \
  acc[0][0] = MFMA16(af0, bf0, acc[0][0], 0, 0, 0); \
  acc[1][0] = MFMA16(af1, bf0, acc[1][0], 0, 0, 0); \
  acc[2][0] = MFMA16(af2, bf0, acc[2][0], 0, 0, 0); \
  acc[3][0] = MFMA16(af3, bf0, acc[3][0], 0, 0, 0); \
  acc[0][1] = MFMA16(af0, bf1, acc[0][1], 0, 0, 0); \
  acc[1][1] = MFMA16(af1, bf1, acc[1][1], 0, 0, 0); \
  acc[2][1] = MFMA16(af2, bf1, acc[2][1], 0, 0, 0); \
  acc[3][1] = MFMA16(af3, bf1, acc[3][1], 0, 0, 0); \
  acc[0][2] = MFMA16(af0, bf2, acc[0][2], 0, 0, 0); \
  acc[1][2] = MFMA16(af1, bf2, acc[1][2], 0, 0, 0); \
  acc[2][2] = MFMA16(af2, bf2, acc[2][2], 0, 0, 0); \
  acc[3][2] = MFMA16(af3, bf2, acc[3][2], 0, 0, 0); \
  acc[0][3] = MFMA16(af0, bf3, acc[0][3], 0, 0, 0); \
  acc[1][3] = MFMA16(af1, bf3, acc[1][3], 0, 0, 0); \
  acc[2][3] = MFMA16(af2, bf3, acc[2][3], 0, 0, 0); \
  acc[3][3] = MFMA16(af3, bf3, acc[3][3], 0, 0, 0); \
  __builtin_amdgcn_s_setprio(0); }while(0)
// 2-barrier K-step: reads -> lgkm0 -> barrier (buf bb free in all waves) ->
// stage t+3 into bb -> MFMAs -> counted vmcnt -> barrier (t+1 resident).
#define TILE3(bb, STG, VMX) do{ \
  DS_ALL(bb); \
  asm volatile("s_waitcnt lgkmcnt(0)" ::: "memory"); \
  __builtin_amdgcn_s_barrier(); \
  STG; \
  MM16; \
  VMX; \
  __builtin_amdgcn_s_barrier(); }while(0)

// common per-thread geometry (4 waves 2x2, 256 threads, 128x128 tile)
#define GEOM_SETUP \
  int tid = threadIdx.x, lane = tid & 63, wave = tid >> 6; \
  int wm = wave >> 1, wn = wave & 1; \
  int l15 = lane & 15, l4 = lane >> 4; \
  int offA0, offA1, offA2, offA3, offB0, offB1, offB2, offB3; \
  { int r; \
    r = wm*64 + 0*16 + l15; offA0 = r*64 + ((l4 ^ ((r>>1)&3)) << 4); \
    r = wm*64 + 1*16 + l15; offA1 = r*64 + ((l4 ^ ((r>>1)&3)) << 4); \
    r = wm*64 + 2*16 + l15; offA2 = r*64 + ((l4 ^ ((r>>1)&3)) << 4); \
    r = wm*64 + 3*16 + l15; offA3 = r*64 + ((l4 ^ ((r>>1)&3)) << 4); \
    r = wn*64 + 0*16 + l15; offB0 = 8192 + r*64 + ((l4 ^ ((r>>1)&3)) << 4); \
    r = wn*64 + 1*16 + l15; offB1 = 8192 + r*64 + ((l4 ^ ((r>>1)&3)) << 4); \
    r = wn*64 + 2*16 + l15; offB2 = 8192 + r*64 + ((l4 ^ ((r>>1)&3)) << 4); \
    r = wn*64 + 3*16 + l15; offB3 = 8192 + r*64 + ((l4 ^ ((r>>1)&3)) << 4); \
  } \
  int rp = tid >> 2, cp = (tid & 3) ^ ((rp >> 1) & 3);  /* stage: row rp(+64), slot tid&3 */

#define ACC_INIT \
  f32x4 acc[4][4]; \
  _Pragma("unroll") for (int m = 0; m < 4; m++) \
  _Pragma("unroll") for (int n = 0; n < 4; n++) \
  _Pragma("unroll") for (int i = 0; i < 4; i++) acc[m][n][i] = 0.f; \
  s16x8 af0, af1, af2, af3, bf0, bf1, bf2, bf3;

// ---------- GEMM1: h[slot][DFF] = relu(x[tok] @ W1[e] + b1[e]); K=512, NT=16 ----------
__global__ __launch_bounds__(256, 3) void k_gemm1(
    const uint16_t* __restrict__ xb, const uint16_t* __restrict__ w1t,
    const float* __restrict__ b1,
    const int* __restrict__ tok_of, const int* __restrict__ offsets,
    const int* __restrict__ trB, const int* __restrict__ texp, const int* __restrict__ ntB,
    uint16_t* __restrict__ h) {
  __shared__ __align__(16) uint16_t smem[24576];   // 48KB: 3 bufs x (A 8KB + B 8KB)
  int id = blockIdx.x;
  int nt = *ntB, tpx = (nt + 7) >> 3;
  int x = id & 7, q = id >> 3, j = q >> 4;
  if (j >= tpx) return;
  int tile = x * tpx + j;
  if (tile >= nt) return;
  int n0 = (q & 15) * 128;
  int e = texp[tile], row0 = trB[tile], end = offsets[e + 1];
  GEOM_SETUP;

  const uint16_t *gA0, *gA1, *gB0, *gB1;
  { int s0 = row0 + rp;      if (s0 >= end) s0 = end - 1;
    int s1 = row0 + rp + 64; if (s1 >= end) s1 = end - 1;
    gA0 = xb + (size_t)tok_of[s0] * DM + cp * 8;
    gA1 = xb + (size_t)tok_of[s1] * DM + cp * 8; }
  { const uint16_t* wb = w1t + (size_t)e * DFF * DM;
    gB0 = wb + (size_t)(n0 + rp +  0) * DM + cp * 8;
    gB1 = wb + (size_t)(n0 + rp + 64) * DM + cp * 8; }

  ACC_INIT;

  SAB_P(0); SAB_P(1); SAB_P(2);                    // tiles 0,1,2 in flight (12 loads)
  VM8;                                             // tile 0 resident
  __builtin_amdgcn_s_barrier();

#pragma unroll 1
  for (int g = 0; g < 4; ++g) {                    // tiles 0..11 (stage t+3 each)
    TILE3(0, SAB_P(0), VM8);
    TILE3(1, SAB_P(1), VM8);
    TILE3(2, SAB_P(2), VM8);
  }
  TILE3(0, SAB_P(0), VM8);                         // tile 12 stages 15
  TILE3(1, NOSTG, VM4);                            // tile 13
  TILE3(2, NOSTG, VM0);                            // tile 14
  TILE3(0, NOSTG, NOVM);                           // tile 15

  // epilogue: bias+relu -> bf16, per-wave LDS repack (row stride 144B, bank-spread)
  {
    float bv[4];
#pragma unroll
    for (int n = 0; n < 4; n++) bv[n] = b1[(size_t)e * DFF + n0 + wn * 64 + n * 16 + l15];
    char* wrg = (char*)smem + wave * 2304;
    int rr = lane >> 2, cb = lane & 3;
#pragma unroll
    for (int m = 0; m < 4; m++) {
#pragma unroll
      for (int n = 0; n < 4; n++)
#pragma unroll
        for (int i = 0; i < 4; i++) {
          float v = fmaxf(acc[m][n][i] + bv[n], 0.f);
          *(uint16_t*)(wrg + (l4 * 4 + i) * 144 + (n * 16 + l15) * 2) = f2b(v);
        }
      int gr = row0 + wm * 64 + m * 16 + rr;
      const char* src = wrg + rr * 144 + cb * 32;
      if (gr < end) {
        uint16_t* dst = h + (size_t)gr * DFF + n0 + wn * 64 + cb * 16;
        *(s16x8*)(dst + 0) = *(const s16x8*)(src +  0);
        *(s16x8*)(dst + 8) = *(const s16x8*)(src + 16);
      }
    }
  }
}

// ---------- GEMM2: y32[pair] = w_of[slot]*(h[slot] @ W2[e] + b2[e]); K=2048, NT=64 ----------
__global__ __launch_bounds__(256, 3) void k_gemm2(
    const uint16_t* __restrict__ h, const uint16_t* __restrict__ w2t,
    const float* __restrict__ b2, const float* __restrict__ w_of,
    const int* __restrict__ pr_of, const int* __restrict__ offsets,
    const int* __restrict__ trB, const int* __restrict__ texp, const int* __restrict__ ntB,
    float* __restrict__ y32) {
  __shared__ __align__(16) uint16_t smem[24576];   // 48KB: 3 bufs x (A 8KB + B 8KB)
  int id = blockIdx.x;
  int nt = *ntB, tpx = (nt + 7) >> 3;
  int x = id & 7, q = id >> 3, j = q >> 2;
  if (j >= tpx) return;
  int tile = x * tpx + j;
  if (tile >= nt) return;
  int n0 = (q & 3) * 128;
  int e = texp[tile], row0 = trB[tile], end = offsets[e + 1];
  GEOM_SETUP;

  const uint16_t *gA0, *gA1, *gB0, *gB1;
  { int s0 = row0 + rp;      if (s0 >= end) s0 = end - 1;
    int s1 = row0 + rp + 64; if (s1 >= end) s1 = end - 1;
    gA0 = h + (size_t)s0 * DFF + cp * 8;
    gA1 = h + (size_t)s1 * DFF + cp * 8; }
  { const uint16_t* wb = w2t + (size_t)e * DM * DFF;
    gB0 = wb + (size_t)(n0 + rp +  0) * DFF + cp * 8;
    gB1 = wb + (size_t)(n0 + rp + 64) * DFF + cp * 8; }

  ACC_INIT;

  SAB_P(0); SAB_P(1); SAB_P(2);
  VM8;
  __builtin_amdgcn_s_barrier();

#pragma unroll 1
  for (int g = 0; g < 20; ++g) {                   // tiles 0..59 (stage t+3 each)
    TILE3(0, SAB_P(0), VM8);
    TILE3(1, SAB_P(1), VM8);
    TILE3(2, SAB_P(2), VM8);
  }
  TILE3(0, SAB_P(0), VM8);                         // tile 60 stages 63
  TILE3(1, NOSTG, VM4);                            // tile 61
  TILE3(2, NOSTG, VM0);                            // tile 62
  TILE3(0, NOSTG, NOVM);                           // tile 63

  // epilogue: weighted bias add, fp32 stores into pair-indexed y32 (16-lane 64B runs)
  {
    float bv[4];
#pragma unroll
    for (int n = 0; n < 4; n++) bv[n] = b2[(size_t)e * DM + n0 + wn * 64 + n * 16 + l15];
#pragma unroll
    for (int m = 0; m < 4; m++)
#pragma unroll
      for (int i = 0; i < 4; i++) {
        int slot = row0 + wm * 64 + m * 16 + l4 * 4 + i;
        if (slot < end) {
          float wgt = w_of[slot];
          int pr = pr_of[slot];                    // pair index = tok*2 + k
          size_t base = (size_t)pr * DM + n0 + wn * 64 + l15;
          y32[base +  0] = wgt * (acc[m][0][i] + bv[0]);
          y32[base + 16] = wgt * (acc[m][1][i] + bv[1]);
          y32[base + 32] = wgt * (acc[m][2][i] + bv[2]);
          y32[base + 48] = wgt * (acc[m][3][i] + bv[3]);
        }
      }
  }
}

// ---------------- combine: out[tok] = y32[2tok] + y32[2tok+1] (streaming) ----------------
__global__ __launch_bounds__(256) void k_combine(const float* __restrict__ y32,
                                                 float* __restrict__ out) {
  int tid = threadIdx.x;
  int tok = blockIdx.x * 2 + (tid >> 7);
  int c4 = (tid & 127) * 4;
  const float4 a = *(const float4*)(y32 + (size_t)(tok * 2)     * DM + c4);
  const float4 b = *(const float4*)(y32 + (size_t)(tok * 2 + 1) * DM + c4);
  *(float4*)(out + (size_t)tok * DM + c4) = make_float4(a.x + b.x, a.y + b.y, a.z + b.z, a.w + b.w);
}

extern "C" void kernel_launch(void* const* d_in, const int* in_sizes, int n_in,
                              void* d_out, int out_size, void* d_ws, size_t ws_size,
                              hipStream_t stream) {
  const float* x  = (const float*)d_in[0];
  const float* wg = (const float*)d_in[1];
  const float* w1 = (const float*)d_in[2];
  const float* b1 = (const float*)d_in[3];
  const float* w2 = (const float*)d_in[4];
  const float* b2 = (const float*)d_in[5];
  float* out = (float*)d_out;

  char* ws = (char*)d_ws;
  const size_t MB = 1024 * 1024;
  uint16_t* xb   = (uint16_t*)ws;                  // [0,16) MB
  uint16_t* w1t  = (uint16_t*)(ws + 16 * MB);      // [16,32) MB  [E][DFF][DM]
  uint16_t* w2t  = (uint16_t*)(ws + 32 * MB);      // [32,48) MB  [E][DM][DFF]
  uint16_t* hbuf = (uint16_t*)(ws + 48 * MB);      // [48,176) MB [NPAIR][DFF]
  int* ctrl = (int*)(ws + 176 * MB);               // [176,177) MB
  int*   counts  = ctrl;                 // 0..8
  int*   cursors = ctrl + 8;             // 8..16
  int*   offsets = ctrl + 16;            // 16..25
  int*   ntB     = ctrl + 32;            // 32
  int*   trB     = ctrl + 64;            // 64..384 (320)
  int*   texp    = ctrl + 384;           // 384..704 (320)
  int*   tk_e    = ctrl + 1024;
  float* tk_w    = (float*)(ctrl + 1024 + 32768);
  int*   tok_of  = ctrl + 1024 + 2 * 32768;
  float* w_of    = (float*)(ctrl + 1024 + 3 * 32768);
  int*   pr_of   = ctrl + 1024 + 4 * 32768;
  float* y32     = (float*)(ws + 177 * MB);        // [177,241) MB fp32 [NPAIR][DM]

  hipMemsetAsync(counts, 0, 16 * sizeof(int), stream);

  k_prep<<<256 + 16384, 256, 0, stream>>>(x, wg, counts, tk_e, tk_w, xb,
                                          w1, w2, w1t, w2t);
  k_build<<<NPAIR / 256, 256, 0, stream>>>(tk_e, tk_w, counts, cursors, tok_of, pr_of, w_of,
                                           offsets, trB, texp, ntB);
  k_gemm1<<<8 * TPXMAX * 16, 256, 0, stream>>>(xb, w1t, b1, tok_of, offsets,
                                               trB, texp, ntB, hbuf);
  k_gemm2<<<8 * TPXMAX * 4, 256, 0, stream>>>(hbuf, w2t, b2, w_of, pr_of, offsets,
                                              trB, texp, ntB, y32);
  k_combine<<<BTOK / 2, 256, 0, stream>>>(y32, out);
}